// Round 12
// baseline (287.270 us; speedup 1.0000x reference)
//
#include <hip/hip_runtime.h>

#define D 64
#define BK_SHIFT 6              // 64 nodes per bucket
#define XCDS 8                  // per-XCD tmp partitions (blockIdx&7 heuristic)
#define TSUB 512                // tmp entries per (bucket,xcd) cell (mean ~200, 22 sigma)
#define TCAP 4096               // XCDS*TSUB = staged entries per bucket
#define CSTRIDE 6144            // col entries per bucket (TCAP + 64*31 pad + slack), 32-aligned
#define NBLK_M 512              // merged binning blocks (multiple of 8)
#define MCH 2560                // staged chunk capacity (ints) per block

__device__ __forceinline__ float bfbits2f(unsigned short b) {
    union { unsigned int u; float f; } c;
    c.u = ((unsigned int)b) << 16;
    return c.f;
}

__device__ __forceinline__ unsigned short f2bfbits(float f) {
    union { float f; unsigned int u; } c;
    c.f = f;
    unsigned int u = c.u;
    unsigned int lsb = (u >> 16) & 1u;
    u += 0x7fffu + lsb;           // round-to-nearest-even
    return (unsigned short)(u >> 16);
}

__device__ __forceinline__ float ldmix(const void* p, size_t i, int isf32) {
    return isf32 ? ((const float*)p)[i] : bfbits2f(((const unsigned short*)p)[i]);
}

__device__ __forceinline__ float rlane(float v, int l) {
    return __int_as_float(__builtin_amdgcn_readlane(__float_as_int(v), l));
}

// bf16-pair unpack, bit-identical to bfbits2f on each half:
__device__ __forceinline__ float lo16f(unsigned int u) { return __uint_as_float(u << 16); }
__device__ __forceinline__ float hi16f(unsigned int u) { return __uint_as_float(u & 0xffff0000u); }

// ---- param conversion (with fused dtype sniff) -----------------------------
#define OW1 0
#define OW2 4096
#define OW3 8192
#define OB1 12288
#define OB2 12352
#define OB3 12416
#define OG  12480
#define OBE 12544
#define OPA 12608

__global__ void cvt_params_kernel(const void* W1, const void* b1, const void* W2, const void* b2,
                                  const void* W3, const void* b3, const void* pa, const void* g,
                                  const void* be, int* __restrict__ flag,
                                  float* __restrict__ P) {
    __shared__ int sbad;
    int t = threadIdx.x;                 // one block of 256
    if (t == 0) sbad = 0;
    __syncthreads();
    {   // sniff: first 256 shorts of W1 interpreted as bf16
        float v = bfbits2f(((const unsigned short*)W1)[t]);
        if (!(v == v) || fabsf(v) > 1e4f) atomicOr(&sbad, 1);
    }
    __syncthreads();
    int isf = sbad ? 1 : 0;
    if (t == 0) *flag = isf;
    for (int i = t; i < D * D; i += 256) {
        P[OW1 + i] = ldmix(W1, i, isf);
        P[OW2 + i] = ldmix(W2, i, isf);
        P[OW3 + i] = ldmix(W3, i, isf);
    }
    if (t < D) {
        P[OB1 + t] = ldmix(b1, t, isf);
        P[OB2 + t] = ldmix(b2, t, isf);
        P[OB3 + t] = ldmix(b3, t, isf);
        P[OG  + t] = ldmix(g,  t, isf);
        P[OBE + t] = ldmix(be, t, isf);
    }
    if (t == 0) P[OPA] = ldmix(pa, 0, isf);
}

// ---- merged binning with XCD-partitioned tmp -------------------------------
// tmp[bucket][xcd][TSUB]: each 64B line is written only by blocks of one
// XCD-residue class -> no cross-XCD L2 line bouncing; per-XCD working set
// 1.6MB < 4MB L2. gcur[bucket][xcd].
__global__ void __launch_bounds__(256)
binAm_kernel(const int* __restrict__ src, const int* __restrict__ dst,
             int E, int NB, int CH, int* __restrict__ gcur,
             unsigned int* __restrict__ tmp) {
    __shared__ int ls[MCH];
    __shared__ int ld[MCH];
    __shared__ int h[1024];
    int t = threadIdx.x, bb = blockIdx.x;
    int xcd = bb & (XCDS - 1);           // dispatch round-robin heuristic (speed-only)
    int beg = bb * CH, end = beg + CH; if (end > E) end = E;
    int m = end - beg;
    bool staged = (m <= MCH);
    for (int i = t; i < NB; i += 256) h[i] = 0;
    __syncthreads();
    for (int i = t; i < m; i += 256) {
        int d = dst[beg + i];
        if (staged) { ld[i] = d; ls[i] = src[beg + i]; }
        atomicAdd(&h[d >> BK_SHIFT], 1);
    }
    __syncthreads();
    for (int b = t; b < NB; b += 256) {
        int c = h[b];
        h[b] = c ? atomicAdd(&gcur[b * XCDS + xcd], c) : 0;
    }
    __syncthreads();
    for (int i = t; i < m; i += 256) {
        int d = staged ? ld[i] : dst[beg + i];
        int s = staged ? ls[i] : src[beg + i];
        int bk = d >> BK_SHIFT;
        int p = atomicAdd(&h[bk], 1);
        if (p < TSUB)
            tmp[((size_t)bk * XCDS + xcd) * TSUB + p] =
                ((unsigned int)s << BK_SHIFT) | (unsigned int)(d & 63);
    }
}

// one block per bucket: read 8 per-XCD sub-runs (contiguous), per-node count +
// padded scan + L2-local scatter + pad-fill + fused layer-1 prescale.
__global__ void binB_kernel(const unsigned int* __restrict__ tmp, const int* __restrict__ gcur,
                            int* __restrict__ row_beg, int* __restrict__ cnt,
                            float* __restrict__ dinv, int* __restrict__ col,
                            const void* __restrict__ X, const int* __restrict__ flag,
                            unsigned short* __restrict__ Xs, int N) {
    __shared__ unsigned int ent[TCAP];
    __shared__ int lv[64], lpv[64], lpe[64], lcur[64];
    __shared__ float ldv[64];
    __shared__ int moff[XCDS + 1];
    int b = blockIdx.x, t = threadIdx.x;
    int colbase = b * CSTRIDE;           // 32-aligned per bucket
    if (t < 64) lv[t] = 0;
    if (t == 0) {
        int s = 0;
        moff[0] = 0;
#pragma unroll
        for (int x = 0; x < XCDS; ++x) {
            int mx = gcur[b * XCDS + x];
            if (mx > TSUB) mx = TSUB;
            s += mx;
            moff[x + 1] = s;
        }
    }
    __syncthreads();
    int mtot = moff[XCDS];
#pragma unroll
    for (int x = 0; x < XCDS; ++x) {
        int base = moff[x];
        int mx = moff[x + 1] - base;
        const unsigned int* tsrc = tmp + ((size_t)b * XCDS + x) * TSUB;
        for (int i = t; i < mx; i += 256) {
            unsigned int e = tsrc[i];
            ent[base + i] = e;
            atomicAdd(&lv[e & 63u], 1);
        }
    }
    __syncthreads();
    if (t < 64) {
        int v  = lv[t];
        int pv = (v + 31) & ~31;             // padded to multiple of 32
        if (pv == 0) pv = 32;                // guarantee >= 1 chunk per node
        int incl = pv;
#pragma unroll
        for (int off = 1; off < 64; off <<= 1) {
            int u = __shfl_up(incl, off, 64);
            if (t >= off) incl += u;
        }
        int pexcl = incl - pv;
        lpv[t]  = pv;
        lpe[t]  = pexcl;
        lcur[t] = pexcl;
        float dv = rsqrtf((float)(v + 1));
        ldv[t] = dv;
        int node = b * 64 + t;
        if (node < N) {
            row_beg[node] = colbase + pexcl;
            cnt[node]     = pv;              // padded count (loop bound)
            dinv[node]    = dv;
        }
    }
    __syncthreads();
    for (int i = t; i < mtot; i += 256) {
        unsigned int e = ent[i];
        int p = atomicAdd(&lcur[e & 63u], 1);
        col[colbase + p] = (int)(e >> BK_SHIFT);
    }
    // pad fill: positions [v, pv) of each node get the zero-row index N
    for (int i = t; i < 64 * 32; i += 256) {
        int nl = i >> 5, j = i & 31;
        int idx = lv[nl] + j;
        if (idx < lpv[nl]) col[colbase + lpe[nl] + idx] = N;
    }
    // fused layer-1 prescale: Xs[node][f] = bf16(dinv * X[node][f])
    int isf = *flag;
    for (int i = t; i < 64 * 64; i += 256) {
        int nl = i >> 6, f = i & 63;
        int node = b * 64 + nl;
        if (node < N)
            Xs[(size_t)node * D + f] = f2bfbits(ldv[nl] * ldmix(X, (size_t)node * D + f, isf));
    }
}

// ---- feature kernels (unchanged from R11 measured-best) --------------------
// 4 nodes per wave, 16+4 row loads in flight, col as one int4/node,
// GEMM via W-transposed-in-LDS (stride 68) + v_readlane x-broadcast.
// R10 lesson: min-waves bound spills (FETCH 43.8->277MB); ~68 VGPR is the
// design floor for the 16-in-flight gather. Default bounds.

__device__ __forceinline__ void acc8(float* a, uint4 v) {
    a[0] += lo16f(v.x); a[1] += hi16f(v.x);
    a[2] += lo16f(v.y); a[3] += hi16f(v.y);
    a[4] += lo16f(v.z); a[5] += hi16f(v.z);
    a[6] += lo16f(v.w); a[7] += hi16f(v.w);
}

__device__ __forceinline__ void agg_tail(const unsigned short* __restrict__ Xs,
                                         const int* __restrict__ col, int beg, int pc,
                                         int slot, int sub, float (&x)[8]) {
    for (int c = 32; c < pc; c += 32) {
        int4 s = *(const int4*)(col + beg + c + 4 * slot);
        uint4 v0 = *((const uint4*)(Xs + ((size_t)s.x << 6)) + sub);
        uint4 v1 = *((const uint4*)(Xs + ((size_t)s.y << 6)) + sub);
        uint4 v2 = *((const uint4*)(Xs + ((size_t)s.z << 6)) + sub);
        uint4 v3 = *((const uint4*)(Xs + ((size_t)s.w << 6)) + sub);
        acc8(x, v0); acc8(x, v1); acc8(x, v2); acc8(x, v3);
    }
}

// aggregation + GEMM for 4 consecutive nodes owned by one wave.
__device__ __forceinline__ void quad_main(const unsigned short* __restrict__ Xs,
        const int* __restrict__ row_beg, const int* __restrict__ cnt,
        const int* __restrict__ col, const float* __restrict__ dinv,
        const float* __restrict__ Wt, int base, int n, int lane,
        float& dn0, float& dn1, float& dn2, float& dn3,
        float& a0, float& a1, float& a2, float& a3)
{
    const int slot = lane >> 3, sub = lane & 7;
    bool v1 = (base + 1) < n, v2 = (base + 2) < n, v3 = (base + 3) < n;
    int i0 = base, i1 = v1 ? base + 1 : n, i2 = v2 ? base + 2 : n, i3 = v3 ? base + 3 : n;
    int beg0 = row_beg[base];
    int beg1 = v1 ? row_beg[base + 1] : beg0;     // invalid -> read node0's (safe, discarded)
    int beg2 = v2 ? row_beg[base + 2] : beg0;
    int beg3 = v3 ? row_beg[base + 3] : beg0;
    int pc0 = cnt[base];
    int pc1 = v1 ? cnt[base + 1] : 32;
    int pc2 = v2 ? cnt[base + 2] : 32;
    int pc3 = v3 ? cnt[base + 3] : 32;
    dn0 = dinv[base];
    dn1 = v1 ? dinv[base + 1] : 0.f;
    dn2 = v2 ? dinv[base + 2] : 0.f;
    dn3 = v3 ? dinv[base + 3] : 0.f;

    // self rows (early issue)
    uint4 sv0 = *((const uint4*)(Xs + ((size_t)i0 << 6)) + sub);
    uint4 sv1 = *((const uint4*)(Xs + ((size_t)i1 << 6)) + sub);
    uint4 sv2 = *((const uint4*)(Xs + ((size_t)i2 << 6)) + sub);
    uint4 sv3 = *((const uint4*)(Xs + ((size_t)i3 << 6)) + sub);
    // first-chunk col indices: one aligned int4 per node (pc >= 32 guaranteed)
    int4 c0 = *(const int4*)(col + beg0 + 4 * slot);
    int4 c1 = *(const int4*)(col + beg1 + 4 * slot);
    int4 c2 = *(const int4*)(col + beg2 + 4 * slot);
    int4 c3 = *(const int4*)(col + beg3 + 4 * slot);
    // 16 row loads in flight
    uint4 r00 = *((const uint4*)(Xs + ((size_t)c0.x << 6)) + sub);
    uint4 r01 = *((const uint4*)(Xs + ((size_t)c0.y << 6)) + sub);
    uint4 r02 = *((const uint4*)(Xs + ((size_t)c0.z << 6)) + sub);
    uint4 r03 = *((const uint4*)(Xs + ((size_t)c0.w << 6)) + sub);
    uint4 r10 = *((const uint4*)(Xs + ((size_t)c1.x << 6)) + sub);
    uint4 r11 = *((const uint4*)(Xs + ((size_t)c1.y << 6)) + sub);
    uint4 r12 = *((const uint4*)(Xs + ((size_t)c1.z << 6)) + sub);
    uint4 r13 = *((const uint4*)(Xs + ((size_t)c1.w << 6)) + sub);
    uint4 r20 = *((const uint4*)(Xs + ((size_t)c2.x << 6)) + sub);
    uint4 r21 = *((const uint4*)(Xs + ((size_t)c2.y << 6)) + sub);
    uint4 r22 = *((const uint4*)(Xs + ((size_t)c2.z << 6)) + sub);
    uint4 r23 = *((const uint4*)(Xs + ((size_t)c2.w << 6)) + sub);
    uint4 r30 = *((const uint4*)(Xs + ((size_t)c3.x << 6)) + sub);
    uint4 r31 = *((const uint4*)(Xs + ((size_t)c3.y << 6)) + sub);
    uint4 r32 = *((const uint4*)(Xs + ((size_t)c3.z << 6)) + sub);
    uint4 r33 = *((const uint4*)(Xs + ((size_t)c3.w << 6)) + sub);

    float x0[8], x1[8], x2[8], x3[8];
#pragma unroll
    for (int j = 0; j < 8; ++j) { x0[j] = 0.f; x1[j] = 0.f; x2[j] = 0.f; x3[j] = 0.f; }
    acc8(x0, r00); acc8(x0, r01); acc8(x0, r02); acc8(x0, r03);
    acc8(x1, r10); acc8(x1, r11); acc8(x1, r12); acc8(x1, r13);
    acc8(x2, r20); acc8(x2, r21); acc8(x2, r22); acc8(x2, r23);
    acc8(x3, r30); acc8(x3, r31); acc8(x3, r32); acc8(x3, r33);
    // rare tails (deg > 32)
    agg_tail(Xs, col, beg0, pc0, slot, sub, x0);
    agg_tail(Xs, col, beg1, pc1, slot, sub, x1);
    agg_tail(Xs, col, beg2, pc2, slot, sub, x2);
    agg_tail(Xs, col, beg3, pc3, slot, sub, x3);
    // reduce across the 8 row-slots (flip lane bits 3..5)
#pragma unroll
    for (int off = 8; off < 64; off <<= 1) {
#pragma unroll
        for (int j = 0; j < 8; ++j) {
            x0[j] += __shfl_xor(x0[j], off, 64);
            x1[j] += __shfl_xor(x1[j], off, 64);
            x2[j] += __shfl_xor(x2[j], off, 64);
            x3[j] += __shfl_xor(x3[j], off, 64);
        }
    }
    // self contribution (added once, post-reduce)
    acc8(x0, sv0); acc8(x1, sv1); acc8(x2, sv2); acc8(x3, sv3);

    // GEMM: out[lane] = sum_k x[k] * W[k][lane]
    a0 = 0.f; a1 = 0.f; a2 = 0.f; a3 = 0.f;
    const float* wt = Wt + lane * 68;
#pragma unroll
    for (int kc = 0; kc < 8; ++kc) {
        float4 wa = *(const float4*)(wt + kc * 8);
        float4 wb = *(const float4*)(wt + kc * 8 + 4);
#define GQ(j, wv) { float w_ = (wv); \
        a0 = fmaf(rlane(x0[j], kc), w_, a0); \
        a1 = fmaf(rlane(x1[j], kc), w_, a1); \
        a2 = fmaf(rlane(x2[j], kc), w_, a2); \
        a3 = fmaf(rlane(x3[j], kc), w_, a3); }
        GQ(0, wa.x) GQ(1, wa.y) GQ(2, wa.z) GQ(3, wa.w)
        GQ(4, wb.x) GQ(5, wb.y) GQ(6, wb.z) GQ(7, wb.w)
#undef GQ
    }
}

__global__ void __launch_bounds__(256)
agg_gemm_kernel(const unsigned short* __restrict__ Xs,
                const int* __restrict__ row_beg, const int* __restrict__ cnt,
                const int* __restrict__ col, const float* __restrict__ dinv,
                const float* __restrict__ W, const float* __restrict__ b,
                const float* __restrict__ pa,
                unsigned short* __restrict__ Xout, int n) {
    __shared__ float Wt[64 * 68];
    int t = threadIdx.x;
    for (int i = t; i < D * D; i += 256) Wt[(i & 63) * 68 + (i >> 6)] = W[i];
    __syncthreads();
    int wid = t >> 6, lane = t & 63;
    int base = blockIdx.x * 16 + wid * 4;
    if (base >= n) return;
    float bl = b[lane];
    float pr = pa[0];
    float dn0, dn1, dn2, dn3, a0, a1, a2, a3;
    quad_main(Xs, row_beg, cnt, col, dinv, Wt, base, n, lane,
              dn0, dn1, dn2, dn3, a0, a1, a2, a3);
    a0 = fmaf(dn0, a0, bl); a1 = fmaf(dn1, a1, bl);
    a2 = fmaf(dn2, a2, bl); a3 = fmaf(dn3, a3, bl);
    a0 = (a0 >= 0.f) ? a0 : pr * a0;
    a1 = (a1 >= 0.f) ? a1 : pr * a1;
    a2 = (a2 >= 0.f) ? a2 : pr * a2;
    a3 = (a3 >= 0.f) ? a3 : pr * a3;
    a0 *= dn0; a1 *= dn1; a2 *= dn2; a3 *= dn3;      // prescale for next layer
    Xout[(size_t)base * D + lane] = f2bfbits(a0);
    if (base + 1 < n) Xout[(size_t)(base + 1) * D + lane] = f2bfbits(a1);
    if (base + 2 < n) Xout[(size_t)(base + 2) * D + lane] = f2bfbits(a2);
    if (base + 3 < n) Xout[(size_t)(base + 3) * D + lane] = f2bfbits(a3);
}

__global__ void __launch_bounds__(256)
agg_gemm_ln_kernel(const unsigned short* __restrict__ Xs,
                   const int* __restrict__ row_beg, const int* __restrict__ cnt,
                   const int* __restrict__ col, const float* __restrict__ dinv,
                   const float* __restrict__ W, const float* __restrict__ b,
                   const float* __restrict__ g, const float* __restrict__ be,
                   const int* __restrict__ flag, void* __restrict__ out, int n) {
    __shared__ float Wt[64 * 68];
    int t = threadIdx.x;
    for (int i = t; i < D * D; i += 256) Wt[(i & 63) * 68 + (i >> 6)] = W[i];
    __syncthreads();
    int wid = t >> 6, lane = t & 63;
    int base = blockIdx.x * 16 + wid * 4;
    if (base >= n) return;
    int   isf = *flag;
    float bl  = b[lane];
    float gl  = g[lane];
    float bel = be[lane];
    float dn0, dn1, dn2, dn3, a0, a1, a2, a3;
    quad_main(Xs, row_beg, cnt, col, dinv, Wt, base, n, lane,
              dn0, dn1, dn2, dn3, a0, a1, a2, a3);
    a0 = fmaf(dn0, a0, bl); a1 = fmaf(dn1, a1, bl);
    a2 = fmaf(dn2, a2, bl); a3 = fmaf(dn3, a3, bl);
    // LayerNorm all 4 nodes across the wave (independent shuffles)
    float s0 = a0, s1 = a1, s2 = a2, s3 = a3;
#pragma unroll
    for (int off = 32; off > 0; off >>= 1) {
        s0 += __shfl_xor(s0, off, 64); s1 += __shfl_xor(s1, off, 64);
        s2 += __shfl_xor(s2, off, 64); s3 += __shfl_xor(s3, off, 64);
    }
    float mu0 = s0 * (1.f / 64.f), mu1 = s1 * (1.f / 64.f);
    float mu2 = s2 * (1.f / 64.f), mu3 = s3 * (1.f / 64.f);
    float d0 = a0 - mu0, d1 = a1 - mu1, d2 = a2 - mu2, d3 = a3 - mu3;
    float q0 = d0 * d0, q1 = d1 * d1, q2 = d2 * d2, q3 = d3 * d3;
#pragma unroll
    for (int off = 32; off > 0; off >>= 1) {
        q0 += __shfl_xor(q0, off, 64); q1 += __shfl_xor(q1, off, 64);
        q2 += __shfl_xor(q2, off, 64); q3 += __shfl_xor(q3, off, 64);
    }
    float r0 = rsqrtf(q0 * (1.f / 64.f) + 1e-5f);
    float r1 = rsqrtf(q1 * (1.f / 64.f) + 1e-5f);
    float r2 = rsqrtf(q2 * (1.f / 64.f) + 1e-5f);
    float r3 = rsqrtf(q3 * (1.f / 64.f) + 1e-5f);
    float o0 = d0 * r0 * gl + bel;
    float o1 = d1 * r1 * gl + bel;
    float o2 = d2 * r2 * gl + bel;
    float o3 = d3 * r3 * gl + bel;
    size_t oi = (size_t)base * D + lane;
    if (isf) {
        ((float*)out)[oi] = o0;
        if (base + 1 < n) ((float*)out)[oi + 64]  = o1;
        if (base + 2 < n) ((float*)out)[oi + 128] = o2;
        if (base + 3 < n) ((float*)out)[oi + 192] = o3;
    } else {
        ((unsigned short*)out)[oi] = f2bfbits(o0);
        if (base + 1 < n) ((unsigned short*)out)[oi + 64]  = f2bfbits(o1);
        if (base + 2 < n) ((unsigned short*)out)[oi + 128] = f2bfbits(o2);
        if (base + 3 < n) ((unsigned short*)out)[oi + 192] = f2bfbits(o3);
    }
}

// ---- driver ----------------------------------------------------------------

extern "C" void kernel_launch(void* const* d_in, const int* in_sizes, int n_in,
                              void* d_out, int out_size, void* d_ws, size_t ws_size,
                              hipStream_t stream) {
    const void* X   = d_in[0];
    const void* W1  = d_in[1];
    const void* b1  = d_in[2];
    const void* W2  = d_in[3];
    const void* b2  = d_in[4];
    const void* W3  = d_in[5];
    const void* b3  = d_in[6];
    const void* pa  = d_in[7];
    const void* g   = d_in[8];
    const void* be  = d_in[9];
    const int*  ei  = (const int*)d_in[10];

    int N = in_sizes[0] / D;
    int E = in_sizes[10] / 2;
    int NB = (N + 63) >> BK_SHIFT;       // <= 1024 for N <= 65536
    int CH = (E + NBLK_M - 1) / NBLK_M;  // edges per merged-binning block
    const int* src = ei;
    const int* dst = ei + E;

    char* p = (char*)d_ws;
    auto alloc = [&](size_t bytes) { void* q = (void*)p; p += (bytes + 255) & ~(size_t)255; return q; };
    int*            flag       = (int*)alloc(4);
    int*            gcur       = (int*)alloc((size_t)NB * XCDS * 4);
    int*            row_beg    = (int*)alloc((size_t)N * 4);
    int*            cnt        = (int*)alloc((size_t)N * 4);
    float*          dinv       = (float*)alloc((size_t)N * 4);
    int*            col        = (int*)alloc((size_t)NB * CSTRIDE * 4);
    unsigned int*   tmp        = (unsigned int*)alloc((size_t)NB * XCDS * TSUB * 4);
    float*          P          = (float*)alloc((size_t)(OPA + 1) * 4);
    unsigned short* Xs         = (unsigned short*)alloc((size_t)(N + 1) * D * 2);
    unsigned short* Xs2        = (unsigned short*)alloc((size_t)(N + 1) * D * 2);
    (void)ws_size; (void)n_in; (void)out_size;

    // per-iteration resets (part of the captured graph)
    (void)hipMemsetAsync(gcur, 0, (size_t)NB * XCDS * 4, stream);
    // zero row (index N) for pad edges
    (void)hipMemsetAsync(Xs  + (size_t)N * D, 0, D * 2, stream);
    (void)hipMemsetAsync(Xs2 + (size_t)N * D, 0, D * 2, stream);

    cvt_params_kernel<<<1, 256, 0, stream>>>(W1, b1, W2, b2, W3, b3, pa, g, be, flag, P);

    binAm_kernel<<<NBLK_M, 256, 0, stream>>>(src, dst, E, NB, CH, gcur, tmp);
    binB_kernel<<<NB, 256, 0, stream>>>(tmp, gcur, row_beg, cnt, dinv, col, X, flag, Xs, N);

    int ngb = (N + 15) / 16;         // 16 nodes per 256-thread block (4 per wave)

    agg_gemm_kernel   <<<ngb, 256, 0, stream>>>(Xs,  row_beg, cnt, col, dinv, P + OW1, P + OB1, P + OPA, Xs2, N);
    agg_gemm_kernel   <<<ngb, 256, 0, stream>>>(Xs2, row_beg, cnt, col, dinv, P + OW2, P + OB2, P + OPA, Xs,  N);
    agg_gemm_ln_kernel<<<ngb, 256, 0, stream>>>(Xs,  row_beg, cnt, col, dinv, P + OW3, P + OB3, P + OG, P + OBE, flag, d_out, N);
}

// Round 13
// 266.447 us; speedup vs baseline: 1.0781x; 1.0781x over previous
//
#include <hip/hip_runtime.h>

#define D 64
#define BK_SHIFT 6              // 64 nodes per bucket
#define TCAP 4096               // fixed tmp entries per bucket (mean ~1600, >50 sigma)
#define CSTRIDE 6144            // col entries per bucket (TCAP + 64*31 pad + slack), 32-aligned
#define NBLK_M 512              // merged binning blocks
#define MCH 2560                // staged chunk capacity (ints) per block

__device__ __forceinline__ float bfbits2f(unsigned short b) {
    union { unsigned int u; float f; } c;
    c.u = ((unsigned int)b) << 16;
    return c.f;
}

__device__ __forceinline__ unsigned short f2bfbits(float f) {
    union { float f; unsigned int u; } c;
    c.f = f;
    unsigned int u = c.u;
    unsigned int lsb = (u >> 16) & 1u;
    u += 0x7fffu + lsb;           // round-to-nearest-even
    return (unsigned short)(u >> 16);
}

__device__ __forceinline__ float ldmix(const void* p, size_t i, int isf32) {
    return isf32 ? ((const float*)p)[i] : bfbits2f(((const unsigned short*)p)[i]);
}

__device__ __forceinline__ float rlane(float v, int l) {
    return __int_as_float(__builtin_amdgcn_readlane(__float_as_int(v), l));
}

// bf16-pair unpack, bit-identical to bfbits2f on each half:
__device__ __forceinline__ float lo16f(unsigned int u) { return __uint_as_float(u << 16); }
__device__ __forceinline__ float hi16f(unsigned int u) { return __uint_as_float(u & 0xffff0000u); }

// ---- param layout ----------------------------------------------------------
#define OW1 0
#define OW2 4096
#define OW3 8192
#define OB1 12288
#define OB2 12352
#define OB3 12416
#define OG  12480
#define OBE 12544
#define OPA 12608

// ---- merged binning + fused param conversion (block 0 tail) ----------------
// R12 lesson: XCD-partitioned tmp was neutral-to-negative -> reverted to the
// R11-measured layout. This round: dispatch count 9->6 (cvt fused here,
// zero-rows written by binB/agg) to test launch-serialization overhead.
__global__ void __launch_bounds__(256)
binAm_kernel(const int* __restrict__ src, const int* __restrict__ dst,
             int E, int NB, int CH, int* __restrict__ gcur,
             unsigned int* __restrict__ tmp,
             const void* W1, const void* b1, const void* W2, const void* b2,
             const void* W3, const void* b3, const void* pa, const void* g,
             const void* be, int* __restrict__ flag, float* __restrict__ P) {
    __shared__ int ls[MCH];
    __shared__ int ld[MCH];
    __shared__ int h[1024];
    int t = threadIdx.x, bb = blockIdx.x;
    int beg = bb * CH, end = beg + CH; if (end > E) end = E;
    int m = end - beg;
    bool staged = (m <= MCH);
    for (int i = t; i < NB; i += 256) h[i] = 0;
    __syncthreads();
    for (int i = t; i < m; i += 256) {
        int d = dst[beg + i];
        if (staged) { ld[i] = d; ls[i] = src[beg + i]; }
        atomicAdd(&h[d >> BK_SHIFT], 1);
    }
    __syncthreads();
    for (int b = t; b < NB; b += 256) {
        int c = h[b];
        h[b] = c ? atomicAdd(&gcur[b], c) : 0;
    }
    __syncthreads();
    for (int i = t; i < m; i += 256) {
        int d = staged ? ld[i] : dst[beg + i];
        int s = staged ? ls[i] : src[beg + i];
        int bk = d >> BK_SHIFT;
        int p = atomicAdd(&h[bk], 1);
        if (p < TCAP)
            tmp[(size_t)bk * TCAP + p] = ((unsigned int)s << BK_SHIFT) | (unsigned int)(d & 63);
    }
    // ---- fused param conversion (block 0 only; tiny, uniform-branch) ----
    if (bb == 0) {
        __syncthreads();                 // h reuse: all scatter reads done
        if (t == 0) h[0] = 0;
        __syncthreads();
        {   // sniff: first 256 shorts of W1 interpreted as bf16
            float v = bfbits2f(((const unsigned short*)W1)[t]);
            if (!(v == v) || fabsf(v) > 1e4f) atomicOr(&h[0], 1);
        }
        __syncthreads();
        int isf = h[0] ? 1 : 0;
        if (t == 0) *flag = isf;
        for (int i = t; i < D * D; i += 256) {
            P[OW1 + i] = ldmix(W1, i, isf);
            P[OW2 + i] = ldmix(W2, i, isf);
            P[OW3 + i] = ldmix(W3, i, isf);
        }
        if (t < D) {
            P[OB1 + t] = ldmix(b1, t, isf);
            P[OB2 + t] = ldmix(b2, t, isf);
            P[OB3 + t] = ldmix(b3, t, isf);
            P[OG  + t] = ldmix(g,  t, isf);
            P[OBE + t] = ldmix(be, t, isf);
        }
        if (t == 0) P[OPA] = ldmix(pa, 0, isf);
    }
}

// one block per bucket: per-node count + padded scan + L2-local scatter +
// pad-fill with zero-row index N + fused layer-1 prescale + Xs zero-row.
__global__ void binB_kernel(const unsigned int* __restrict__ tmp, const int* __restrict__ gcur,
                            int* __restrict__ row_beg, int* __restrict__ cnt,
                            float* __restrict__ dinv, int* __restrict__ col,
                            const void* __restrict__ X, const int* __restrict__ flag,
                            unsigned short* __restrict__ Xs, int N) {
    __shared__ unsigned int ent[TCAP];
    __shared__ int lv[64], lpv[64], lpe[64], lcur[64];
    __shared__ float ldv[64];
    int b = blockIdx.x, t = threadIdx.x;
    int beg = b * TCAP;
    int colbase = b * CSTRIDE;           // 32-aligned per bucket
    int m = gcur[b]; if (m > TCAP) m = TCAP;
    if (b == 0 && t < D) Xs[(size_t)N * D + t] = 0;   // zero row for pad edges
    if (t < 64) lv[t] = 0;
    __syncthreads();
    for (int i = t; i < m; i += 256) {
        unsigned int e = tmp[beg + i];
        ent[i] = e;
        atomicAdd(&lv[e & 63u], 1);
    }
    __syncthreads();
    if (t < 64) {
        int v  = lv[t];
        int pv = (v + 31) & ~31;             // padded to multiple of 32
        if (pv == 0) pv = 32;                // guarantee >= 1 chunk per node
        int incl = pv;
#pragma unroll
        for (int off = 1; off < 64; off <<= 1) {
            int u = __shfl_up(incl, off, 64);
            if (t >= off) incl += u;
        }
        int pexcl = incl - pv;
        lpv[t]  = pv;
        lpe[t]  = pexcl;
        lcur[t] = pexcl;
        float dv = rsqrtf((float)(v + 1));
        ldv[t] = dv;
        int node = b * 64 + t;
        if (node < N) {
            row_beg[node] = colbase + pexcl;
            cnt[node]     = pv;              // padded count (loop bound)
            dinv[node]    = dv;
        }
    }
    __syncthreads();
    for (int i = t; i < m; i += 256) {
        unsigned int e = ent[i];
        int p = atomicAdd(&lcur[e & 63u], 1);
        col[colbase + p] = (int)(e >> BK_SHIFT);
    }
    // pad fill: positions [v, pv) of each node get the zero-row index N
    for (int i = t; i < 64 * 32; i += 256) {
        int nl = i >> 5, j = i & 31;
        int idx = lv[nl] + j;
        if (idx < lpv[nl]) col[colbase + lpe[nl] + idx] = N;
    }
    // fused layer-1 prescale: Xs[node][f] = bf16(dinv * X[node][f])
    int isf = *flag;
    for (int i = t; i < 64 * 64; i += 256) {
        int nl = i >> 6, f = i & 63;
        int node = b * 64 + nl;
        if (node < N)
            Xs[(size_t)node * D + f] = f2bfbits(ldv[nl] * ldmix(X, (size_t)node * D + f, isf));
    }
}

// ---- feature kernels (unchanged from R11 measured-best) --------------------
// 4 nodes per wave, 16+4 row loads in flight, col as one int4/node,
// GEMM via W-transposed-in-LDS (stride 68) + v_readlane x-broadcast.
// R10 lesson: min-waves bound spills; ~68 VGPR is the design floor for the
// 16-in-flight gather. Default bounds.

__device__ __forceinline__ void acc8(float* a, uint4 v) {
    a[0] += lo16f(v.x); a[1] += hi16f(v.x);
    a[2] += lo16f(v.y); a[3] += hi16f(v.y);
    a[4] += lo16f(v.z); a[5] += hi16f(v.z);
    a[6] += lo16f(v.w); a[7] += hi16f(v.w);
}

__device__ __forceinline__ void agg_tail(const unsigned short* __restrict__ Xs,
                                         const int* __restrict__ col, int beg, int pc,
                                         int slot, int sub, float (&x)[8]) {
    for (int c = 32; c < pc; c += 32) {
        int4 s = *(const int4*)(col + beg + c + 4 * slot);
        uint4 v0 = *((const uint4*)(Xs + ((size_t)s.x << 6)) + sub);
        uint4 v1 = *((const uint4*)(Xs + ((size_t)s.y << 6)) + sub);
        uint4 v2 = *((const uint4*)(Xs + ((size_t)s.z << 6)) + sub);
        uint4 v3 = *((const uint4*)(Xs + ((size_t)s.w << 6)) + sub);
        acc8(x, v0); acc8(x, v1); acc8(x, v2); acc8(x, v3);
    }
}

// aggregation + GEMM for 4 consecutive nodes owned by one wave.
__device__ __forceinline__ void quad_main(const unsigned short* __restrict__ Xs,
        const int* __restrict__ row_beg, const int* __restrict__ cnt,
        const int* __restrict__ col, const float* __restrict__ dinv,
        const float* __restrict__ Wt, int base, int n, int lane,
        float& dn0, float& dn1, float& dn2, float& dn3,
        float& a0, float& a1, float& a2, float& a3)
{
    const int slot = lane >> 3, sub = lane & 7;
    bool v1 = (base + 1) < n, v2 = (base + 2) < n, v3 = (base + 3) < n;
    int i0 = base, i1 = v1 ? base + 1 : n, i2 = v2 ? base + 2 : n, i3 = v3 ? base + 3 : n;
    int beg0 = row_beg[base];
    int beg1 = v1 ? row_beg[base + 1] : beg0;     // invalid -> read node0's (safe, discarded)
    int beg2 = v2 ? row_beg[base + 2] : beg0;
    int beg3 = v3 ? row_beg[base + 3] : beg0;
    int pc0 = cnt[base];
    int pc1 = v1 ? cnt[base + 1] : 32;
    int pc2 = v2 ? cnt[base + 2] : 32;
    int pc3 = v3 ? cnt[base + 3] : 32;
    dn0 = dinv[base];
    dn1 = v1 ? dinv[base + 1] : 0.f;
    dn2 = v2 ? dinv[base + 2] : 0.f;
    dn3 = v3 ? dinv[base + 3] : 0.f;

    // self rows (early issue)
    uint4 sv0 = *((const uint4*)(Xs + ((size_t)i0 << 6)) + sub);
    uint4 sv1 = *((const uint4*)(Xs + ((size_t)i1 << 6)) + sub);
    uint4 sv2 = *((const uint4*)(Xs + ((size_t)i2 << 6)) + sub);
    uint4 sv3 = *((const uint4*)(Xs + ((size_t)i3 << 6)) + sub);
    // first-chunk col indices: one aligned int4 per node (pc >= 32 guaranteed)
    int4 c0 = *(const int4*)(col + beg0 + 4 * slot);
    int4 c1 = *(const int4*)(col + beg1 + 4 * slot);
    int4 c2 = *(const int4*)(col + beg2 + 4 * slot);
    int4 c3 = *(const int4*)(col + beg3 + 4 * slot);
    // 16 row loads in flight
    uint4 r00 = *((const uint4*)(Xs + ((size_t)c0.x << 6)) + sub);
    uint4 r01 = *((const uint4*)(Xs + ((size_t)c0.y << 6)) + sub);
    uint4 r02 = *((const uint4*)(Xs + ((size_t)c0.z << 6)) + sub);
    uint4 r03 = *((const uint4*)(Xs + ((size_t)c0.w << 6)) + sub);
    uint4 r10 = *((const uint4*)(Xs + ((size_t)c1.x << 6)) + sub);
    uint4 r11 = *((const uint4*)(Xs + ((size_t)c1.y << 6)) + sub);
    uint4 r12 = *((const uint4*)(Xs + ((size_t)c1.z << 6)) + sub);
    uint4 r13 = *((const uint4*)(Xs + ((size_t)c1.w << 6)) + sub);
    uint4 r20 = *((const uint4*)(Xs + ((size_t)c2.x << 6)) + sub);
    uint4 r21 = *((const uint4*)(Xs + ((size_t)c2.y << 6)) + sub);
    uint4 r22 = *((const uint4*)(Xs + ((size_t)c2.z << 6)) + sub);
    uint4 r23 = *((const uint4*)(Xs + ((size_t)c2.w << 6)) + sub);
    uint4 r30 = *((const uint4*)(Xs + ((size_t)c3.x << 6)) + sub);
    uint4 r31 = *((const uint4*)(Xs + ((size_t)c3.y << 6)) + sub);
    uint4 r32 = *((const uint4*)(Xs + ((size_t)c3.z << 6)) + sub);
    uint4 r33 = *((const uint4*)(Xs + ((size_t)c3.w << 6)) + sub);

    float x0[8], x1[8], x2[8], x3[8];
#pragma unroll
    for (int j = 0; j < 8; ++j) { x0[j] = 0.f; x1[j] = 0.f; x2[j] = 0.f; x3[j] = 0.f; }
    acc8(x0, r00); acc8(x0, r01); acc8(x0, r02); acc8(x0, r03);
    acc8(x1, r10); acc8(x1, r11); acc8(x1, r12); acc8(x1, r13);
    acc8(x2, r20); acc8(x2, r21); acc8(x2, r22); acc8(x2, r23);
    acc8(x3, r30); acc8(x3, r31); acc8(x3, r32); acc8(x3, r33);
    // rare tails (deg > 32)
    agg_tail(Xs, col, beg0, pc0, slot, sub, x0);
    agg_tail(Xs, col, beg1, pc1, slot, sub, x1);
    agg_tail(Xs, col, beg2, pc2, slot, sub, x2);
    agg_tail(Xs, col, beg3, pc3, slot, sub, x3);
    // reduce across the 8 row-slots (flip lane bits 3..5)
#pragma unroll
    for (int off = 8; off < 64; off <<= 1) {
#pragma unroll
        for (int j = 0; j < 8; ++j) {
            x0[j] += __shfl_xor(x0[j], off, 64);
            x1[j] += __shfl_xor(x1[j], off, 64);
            x2[j] += __shfl_xor(x2[j], off, 64);
            x3[j] += __shfl_xor(x3[j], off, 64);
        }
    }
    // self contribution (added once, post-reduce)
    acc8(x0, sv0); acc8(x1, sv1); acc8(x2, sv2); acc8(x3, sv3);

    // GEMM: out[lane] = sum_k x[k] * W[k][lane]
    a0 = 0.f; a1 = 0.f; a2 = 0.f; a3 = 0.f;
    const float* wt = Wt + lane * 68;
#pragma unroll
    for (int kc = 0; kc < 8; ++kc) {
        float4 wa = *(const float4*)(wt + kc * 8);
        float4 wb = *(const float4*)(wt + kc * 8 + 4);
#define GQ(j, wv) { float w_ = (wv); \
        a0 = fmaf(rlane(x0[j], kc), w_, a0); \
        a1 = fmaf(rlane(x1[j], kc), w_, a1); \
        a2 = fmaf(rlane(x2[j], kc), w_, a2); \
        a3 = fmaf(rlane(x3[j], kc), w_, a3); }
        GQ(0, wa.x) GQ(1, wa.y) GQ(2, wa.z) GQ(3, wa.w)
        GQ(4, wb.x) GQ(5, wb.y) GQ(6, wb.z) GQ(7, wb.w)
#undef GQ
    }
}

__global__ void __launch_bounds__(256)
agg_gemm_kernel(const unsigned short* __restrict__ Xs,
                const int* __restrict__ row_beg, const int* __restrict__ cnt,
                const int* __restrict__ col, const float* __restrict__ dinv,
                const float* __restrict__ W, const float* __restrict__ b,
                const float* __restrict__ pa,
                unsigned short* __restrict__ Xout, int n) {
    __shared__ float Wt[64 * 68];
    int t = threadIdx.x;
    for (int i = t; i < D * D; i += 256) Wt[(i & 63) * 68 + (i >> 6)] = W[i];
    __syncthreads();
    // zero row N of the OUTPUT table (read only by the next kernel)
    if (blockIdx.x == 0 && t < D) Xout[(size_t)n * D + t] = 0;
    int wid = t >> 6, lane = t & 63;
    int base = blockIdx.x * 16 + wid * 4;
    if (base >= n) return;
    float bl = b[lane];
    float pr = pa[0];
    float dn0, dn1, dn2, dn3, a0, a1, a2, a3;
    quad_main(Xs, row_beg, cnt, col, dinv, Wt, base, n, lane,
              dn0, dn1, dn2, dn3, a0, a1, a2, a3);
    a0 = fmaf(dn0, a0, bl); a1 = fmaf(dn1, a1, bl);
    a2 = fmaf(dn2, a2, bl); a3 = fmaf(dn3, a3, bl);
    a0 = (a0 >= 0.f) ? a0 : pr * a0;
    a1 = (a1 >= 0.f) ? a1 : pr * a1;
    a2 = (a2 >= 0.f) ? a2 : pr * a2;
    a3 = (a3 >= 0.f) ? a3 : pr * a3;
    a0 *= dn0; a1 *= dn1; a2 *= dn2; a3 *= dn3;      // prescale for next layer
    Xout[(size_t)base * D + lane] = f2bfbits(a0);
    if (base + 1 < n) Xout[(size_t)(base + 1) * D + lane] = f2bfbits(a1);
    if (base + 2 < n) Xout[(size_t)(base + 2) * D + lane] = f2bfbits(a2);
    if (base + 3 < n) Xout[(size_t)(base + 3) * D + lane] = f2bfbits(a3);
}

__global__ void __launch_bounds__(256)
agg_gemm_ln_kernel(const unsigned short* __restrict__ Xs,
                   const int* __restrict__ row_beg, const int* __restrict__ cnt,
                   const int* __restrict__ col, const float* __restrict__ dinv,
                   const float* __restrict__ W, const float* __restrict__ b,
                   const float* __restrict__ g, const float* __restrict__ be,
                   const int* __restrict__ flag, void* __restrict__ out, int n) {
    __shared__ float Wt[64 * 68];
    int t = threadIdx.x;
    for (int i = t; i < D * D; i += 256) Wt[(i & 63) * 68 + (i >> 6)] = W[i];
    __syncthreads();
    int wid = t >> 6, lane = t & 63;
    int base = blockIdx.x * 16 + wid * 4;
    if (base >= n) return;
    int   isf = *flag;
    float bl  = b[lane];
    float gl  = g[lane];
    float bel = be[lane];
    float dn0, dn1, dn2, dn3, a0, a1, a2, a3;
    quad_main(Xs, row_beg, cnt, col, dinv, Wt, base, n, lane,
              dn0, dn1, dn2, dn3, a0, a1, a2, a3);
    a0 = fmaf(dn0, a0, bl); a1 = fmaf(dn1, a1, bl);
    a2 = fmaf(dn2, a2, bl); a3 = fmaf(dn3, a3, bl);
    // LayerNorm all 4 nodes across the wave (independent shuffles)
    float s0 = a0, s1 = a1, s2 = a2, s3 = a3;
#pragma unroll
    for (int off = 32; off > 0; off >>= 1) {
        s0 += __shfl_xor(s0, off, 64); s1 += __shfl_xor(s1, off, 64);
        s2 += __shfl_xor(s2, off, 64); s3 += __shfl_xor(s3, off, 64);
    }
    float mu0 = s0 * (1.f / 64.f), mu1 = s1 * (1.f / 64.f);
    float mu2 = s2 * (1.f / 64.f), mu3 = s3 * (1.f / 64.f);
    float d0 = a0 - mu0, d1 = a1 - mu1, d2 = a2 - mu2, d3 = a3 - mu3;
    float q0 = d0 * d0, q1 = d1 * d1, q2 = d2 * d2, q3 = d3 * d3;
#pragma unroll
    for (int off = 32; off > 0; off >>= 1) {
        q0 += __shfl_xor(q0, off, 64); q1 += __shfl_xor(q1, off, 64);
        q2 += __shfl_xor(q2, off, 64); q3 += __shfl_xor(q3, off, 64);
    }
    float r0 = rsqrtf(q0 * (1.f / 64.f) + 1e-5f);
    float r1 = rsqrtf(q1 * (1.f / 64.f) + 1e-5f);
    float r2 = rsqrtf(q2 * (1.f / 64.f) + 1e-5f);
    float r3 = rsqrtf(q3 * (1.f / 64.f) + 1e-5f);
    float o0 = d0 * r0 * gl + bel;
    float o1 = d1 * r1 * gl + bel;
    float o2 = d2 * r2 * gl + bel;
    float o3 = d3 * r3 * gl + bel;
    size_t oi = (size_t)base * D + lane;
    if (isf) {
        ((float*)out)[oi] = o0;
        if (base + 1 < n) ((float*)out)[oi + 64]  = o1;
        if (base + 2 < n) ((float*)out)[oi + 128] = o2;
        if (base + 3 < n) ((float*)out)[oi + 192] = o3;
    } else {
        ((unsigned short*)out)[oi] = f2bfbits(o0);
        if (base + 1 < n) ((unsigned short*)out)[oi + 64]  = f2bfbits(o1);
        if (base + 2 < n) ((unsigned short*)out)[oi + 128] = f2bfbits(o2);
        if (base + 3 < n) ((unsigned short*)out)[oi + 192] = f2bfbits(o3);
    }
}

// ---- driver ----------------------------------------------------------------

extern "C" void kernel_launch(void* const* d_in, const int* in_sizes, int n_in,
                              void* d_out, int out_size, void* d_ws, size_t ws_size,
                              hipStream_t stream) {
    const void* X   = d_in[0];
    const void* W1  = d_in[1];
    const void* b1  = d_in[2];
    const void* W2  = d_in[3];
    const void* b2  = d_in[4];
    const void* W3  = d_in[5];
    const void* b3  = d_in[6];
    const void* pa  = d_in[7];
    const void* g   = d_in[8];
    const void* be  = d_in[9];
    const int*  ei  = (const int*)d_in[10];

    int N = in_sizes[0] / D;
    int E = in_sizes[10] / 2;
    int NB = (N + 63) >> BK_SHIFT;       // <= 1024 for N <= 65536
    int CH = (E + NBLK_M - 1) / NBLK_M;  // edges per merged-binning block
    const int* src = ei;
    const int* dst = ei + E;

    char* p = (char*)d_ws;
    auto alloc = [&](size_t bytes) { void* q = (void*)p; p += (bytes + 255) & ~(size_t)255; return q; };
    int*            flag       = (int*)alloc(4);
    int*            gcur       = (int*)alloc((size_t)NB * 4);
    int*            row_beg    = (int*)alloc((size_t)N * 4);
    int*            cnt        = (int*)alloc((size_t)N * 4);
    float*          dinv       = (float*)alloc((size_t)N * 4);
    int*            col        = (int*)alloc((size_t)NB * CSTRIDE * 4);
    unsigned int*   tmp        = (unsigned int*)alloc((size_t)NB * TCAP * 4);
    float*          P          = (float*)alloc((size_t)(OPA + 1) * 4);
    unsigned short* Xs         = (unsigned short*)alloc((size_t)(N + 1) * D * 2);
    unsigned short* Xs2        = (unsigned short*)alloc((size_t)(N + 1) * D * 2);
    (void)ws_size; (void)n_in; (void)out_size;

    // single per-iteration reset (gcur must be zero before binAm's atomics)
    (void)hipMemsetAsync(gcur, 0, (size_t)NB * 4, stream);

    binAm_kernel<<<NBLK_M, 256, 0, stream>>>(src, dst, E, NB, CH, gcur, tmp,
                                             W1, b1, W2, b2, W3, b3, pa, g, be, flag, P);
    binB_kernel<<<NB, 256, 0, stream>>>(tmp, gcur, row_beg, cnt, dinv, col, X, flag, Xs, N);

    int ngb = (N + 15) / 16;         // 16 nodes per 256-thread block (4 per wave)

    agg_gemm_kernel   <<<ngb, 256, 0, stream>>>(Xs,  row_beg, cnt, col, dinv, P + OW1, P + OB1, P + OPA, Xs2, N);
    agg_gemm_kernel   <<<ngb, 256, 0, stream>>>(Xs2, row_beg, cnt, col, dinv, P + OW2, P + OB2, P + OPA, Xs,  N);
    agg_gemm_ln_kernel<<<ngb, 256, 0, stream>>>(Xs,  row_beg, cnt, col, dinv, P + OW3, P + OB3, P + OG, P + OBE, flag, d_out, N);
}